// Round 8
// baseline (1421.217 us; speedup 1.0000x reference)
//
#include <hip/hip_runtime.h>
#include <cstdint>
#include <cstddef>

#define Nn 102400
#define Ff 400
#define Ee 1638400
#define Kk 300
#define Bb 256
#define CAP 64

// XLA/Eigen f32 rational tanh approximation (ElementalIrEmitter::EmitTanh).
// Evaluated with UNFUSED mul/add (XLA emits plain fmul/fadd, no contraction),
// so CPU(np-ref) and this agree bitwise given bit-identical inputs.
__device__ __forceinline__ float xla_tanhf(float x) {
    const float c = 7.90531110763549805f;
    float xc = fminf(fmaxf(x, -c), c);
    float x2 = __fmul_rn(xc, xc);
    float p = -2.76076847742355e-16f;
    p = __fadd_rn(__fmul_rn(p, x2),  2.00018790482477e-13f);
    p = __fadd_rn(__fmul_rn(p, x2), -8.60467152213735e-11f);
    p = __fadd_rn(__fmul_rn(p, x2),  5.12229709037114e-08f);
    p = __fadd_rn(__fmul_rn(p, x2),  1.48572235717979e-05f);
    p = __fadd_rn(__fmul_rn(p, x2),  6.37261928875436e-04f);
    p = __fadd_rn(__fmul_rn(p, x2),  4.89352455891786e-03f);
    p = __fmul_rn(p, xc);
    float q = 1.19825839466702e-06f;
    q = __fadd_rn(__fmul_rn(q, x2), 1.18534705686654e-04f);
    q = __fadd_rn(__fmul_rn(q, x2), 2.26843463243900e-03f);
    q = __fadd_rn(__fmul_rn(q, x2), 4.89352518554385e-03f);
    float r = __fdiv_rn(p, q);
    return (fabsf(x) < 0.0004f) ? x : r;
}

// ---------------- CSR build: 2 edges/thread, padded fill (64B/counter) -------
__global__ void scat_k(const int* __restrict__ ei, int* __restrict__ fill,
                       int* __restrict__ csr) {
    int g = blockIdx.x * 256 + threadIdx.x;
    int2 d2 = *(const int2*)(ei + Ee + 2 * g);
    int e0 = 2 * g, e1 = 2 * g + 1;
    int p0 = atomicAdd(&fill[(size_t)d2.x * 16], 1);
    int p1 = atomicAdd(&fill[(size_t)d2.y * 16], 1);
    if (p0 < CAP) csr[(size_t)d2.x * CAP + p0] = e0;   // edge id, not src
    if (p1 < CAP) csr[(size_t)d2.y * CAP + p1] = e1;
}

// dis = 1/sqrt(deg+1) fp32 (two correctly-rounded ops = XLA-CPU rsqrt
// lowering); compact degree out of the padded counters.
__global__ void dis_k(const int* __restrict__ fill, float* __restrict__ dis,
                      int* __restrict__ degc) {
    int v = blockIdx.x * 256 + threadIdx.x;
    if (v >= Nn) return;
    int d = fill[(size_t)v * 16];
    degc[v] = d;
    dis[v] = 1.0f / sqrtf((float)(d + 1));   // +1 self loop
}

// ---- 2-wave fp32 GEMM: [M,400]@[400,64], 32x64 tile per 128-thread block,
// tile columns split across 2 waves. A/B staged into LDS once per tile.
// r7-validated: removed gemm from the profile top-5. ONE fma per k, ascending
// -> replicates Eigen gebp.
template <int CH>   // K = 16*CH
__global__ __launch_bounds__(128) void gemm_2w(const float* __restrict__ A,
                                               const float* __restrict__ B,
                                               float* __restrict__ C) {
    constexpr int K = 16 * CH;
    __shared__ __align__(16) float As[16 * 32];
    __shared__ __align__(16) float Bs[16 * 68];
    int tid = threadIdx.x;
    int w = tid >> 6;             // wave id: cols w*32..w*32+31
    int lane = tid & 63;
    int tx = lane & 15;           // col pair {w*32+2tx, w*32+2tx+1}
    int ty = lane >> 4;           // rows ty*8..+7
    int base = blockIdx.x * 32;
    int sr = tid >> 2, sq = tid & 3;        // A staging: row sr(0..31), k-quad sq
    int bk = tid >> 3, bn = (tid & 7) * 8;  // B staging: k-row bk(0..15), 8 cols
    float acc[8][2] = {};
    for (int ch = 0; ch < CH; ++ch) {
        int k0 = ch * 16;
        float4 av = *(const float4*)(A + (size_t)(base + sr) * K + k0 + sq * 4);
        const float* bp = B + (size_t)(k0 + bk) * 64 + bn;
        float4 b0 = *(const float4*)(bp);
        float4 b1 = *(const float4*)(bp + 4);
        __syncthreads();
        As[(sq * 4 + 0) * 32 + sr] = av.x;
        As[(sq * 4 + 1) * 32 + sr] = av.y;
        As[(sq * 4 + 2) * 32 + sr] = av.z;
        As[(sq * 4 + 3) * 32 + sr] = av.w;
        *(float4*)&Bs[bk * 68 + bn]     = b0;
        *(float4*)&Bs[bk * 68 + bn + 4] = b1;
        __syncthreads();
#pragma unroll
        for (int kk = 0; kk < 16; ++kk) {
            float4 f0 = *(const float4*)&As[kk * 32 + ty * 8];
            float4 f1 = *(const float4*)&As[kk * 32 + ty * 8 + 4];
            float2 bb = *(const float2*)&Bs[kk * 68 + w * 32 + tx * 2];
            float av8[8] = {f0.x, f0.y, f0.z, f0.w, f1.x, f1.y, f1.z, f1.w};
#pragma unroll
            for (int r = 0; r < 8; ++r) {
                acc[r][0] = fmaf(av8[r], bb.x, acc[r][0]);
                acc[r][1] = fmaf(av8[r], bb.y, acc[r][1]);
            }
        }
    }
#pragma unroll
    for (int r = 0; r < 8; ++r) {
        float* cp = C + (size_t)(base + ty * 8 + r) * 64 + w * 32 + tx * 2;
        *(float2*)cp = make_float2(acc[r][0], acc[r][1]);
    }
}

// ------- out = xla_tanh(b + segment_sum(norm_e * t[src_e]) ), fp32 exact-order,
// 2 ROWS PER WAVE (both gather windows in flight; the two serial fadd chains
// interleaved -> ILP 2; per-row op order unchanged -> bit-identical).
// PHASE 1 folds the old sortrow_k (bitonic edge-id sort, src/dis gather,
// sorted-row + nrm writeback). Rows padded to 32 with nr=0,u=v: pads add
// exact +0 (acc starts +0, no product flips sign). EPI: 0 = none, 1 = fused
// t4 = h.W4 (r2-validated shfl chain), 64 = fused next-layer GEMM
// t_next[v][c] = sum_k h[v][k]*W[k][c], k ascending, one fma per k -> exact
// Eigen gebp order (same chain the standalone gemm used).
template <int PHASE, int EPI>
__global__ __launch_bounds__(256, 4) void agg64_k(const float* __restrict__ t,
                                                  const float* __restrict__ bias,
                                                  const float* __restrict__ dis,
                                                  const int* __restrict__ degc,
                                                  const int* __restrict__ ei,
                                                  int* __restrict__ csr,
                                                  float* __restrict__ nrm,
                                                  float* __restrict__ out,
                                                  const float* __restrict__ W,
                                                  float* __restrict__ tn) {
    __shared__ int   sidx[8][64];
    __shared__ float snr[8][64];
    __shared__ float sW[EPI == 64 ? 64 * 64 : 1];
    int tid = threadIdx.x;
    int lane = tid & 63;
    int wv = __builtin_amdgcn_readfirstlane(tid >> 6);
    if (EPI == 64) {
        for (int i = tid; i < 64 * 64; i += 256) sW[i] = W[i];
        __syncthreads();   // once per block, before any LDS use
    }
    int v0 = blockIdx.x * 8 + wv * 2;
    int v1 = v0 + 1;
    int s0 = wv * 2, s1 = s0 + 1;

    auto prep = [&](int v, int slot) -> int {
        int dv = __builtin_amdgcn_readfirstlane(min(degc[v], CAP));
        float dsv = dis[v];
        int idxl; float nr;
        if (PHASE == 1) {
            int key = (lane < dv) ? csr[(size_t)v * CAP + lane] : 0x7FFFFFFF;
#pragma unroll
            for (int k = 2; k <= 64; k <<= 1) {
#pragma unroll
                for (int j = k >> 1; j; j >>= 1) {
                    int other = __shfl_xor(key, j);
                    bool up = ((lane & k) == 0);
                    bool lower = ((lane & j) == 0);
                    key = (lower == up) ? min(key, other) : max(key, other);
                }
            }
            idxl = v;                                  // pad u = v
            if (lane < dv) idxl = ei[key];             // src of that edge
            nr = (lane < dv) ? __fmul_rn(dis[idxl], dsv) : 0.0f;
            csr[(size_t)v * CAP + lane] = idxl;        // sorted src row
            nrm[(size_t)v * 64 + lane] = nr;
        } else {
            idxl = (lane < dv) ? csr[(size_t)v * CAP + lane] : v;
            nr = nrm[(size_t)v * 64 + lane];           // pads are 0
        }
        sidx[slot][lane] = idxl;
        snr[slot][lane] = nr;
        return dv;
    };
    int dv0 = prep(v0, s0);
    int dv1 = prep(v1, s1);
    float dsv0 = dis[v0], dsv1 = dis[v1];
    float tself0 = t[(size_t)v0 * 64 + lane];
    float tself1 = t[(size_t)v1 * 64 + lane];
    float bsl = bias[lane];

    // window 0 for BOTH rows issued back-to-back (2x MLP); pads gather t[v]
    // (cached) and contribute exact +0 in the chain.
    float tv0[32], tv1[32];
#pragma unroll
    for (int q = 0; q < 32; ++q) {
        int u = __builtin_amdgcn_readfirstlane(sidx[s0][q]);
        tv0[q] = t[(size_t)u * 64 + lane];
    }
#pragma unroll
    for (int q = 0; q < 32; ++q) {
        int u = __builtin_amdgcn_readfirstlane(sidx[s1][q]);
        tv1[q] = t[(size_t)u * 64 + lane];
    }
    float acc0 = 0.0f, acc1 = 0.0f;
#pragma unroll
    for (int q = 0; q < 32; ++q) {   // two independent chains, ILP 2
        acc0 = __fadd_rn(acc0, __fmul_rn(tv0[q], snr[s0][q]));
        acc1 = __fadd_rn(acc1, __fmul_rn(tv1[q], snr[s1][q]));
    }
    // rare second window (dv > 32), appended in order per row
    if (dv0 > 32) {
        float tw[32];
#pragma unroll
        for (int q = 0; q < 32; ++q) {
            int u = __builtin_amdgcn_readfirstlane(sidx[s0][32 + q]);
            tw[q] = t[(size_t)u * 64 + lane];
        }
#pragma unroll
        for (int q = 0; q < 32; ++q)
            acc0 = __fadd_rn(acc0, __fmul_rn(tw[q], snr[s0][32 + q]));
    }
    if (dv1 > 32) {
        float tw[32];
#pragma unroll
        for (int q = 0; q < 32; ++q) {
            int u = __builtin_amdgcn_readfirstlane(sidx[s1][32 + q]);
            tw[q] = t[(size_t)u * 64 + lane];
        }
#pragma unroll
        for (int q = 0; q < 32; ++q)
            acc1 = __fadd_rn(acc1, __fmul_rn(tw[q], snr[s1][32 + q]));
    }
    // self-loop last (ref appends loops after edges)
    acc0 = __fadd_rn(acc0, __fmul_rn(tself0, __fmul_rn(dsv0, dsv0)));
    acc1 = __fadd_rn(acc1, __fmul_rn(tself1, __fmul_rn(dsv1, dsv1)));
    float res0 = xla_tanhf(__fadd_rn(acc0, bsl));
    float res1 = xla_tanhf(__fadd_rn(acc1, bsl));
    out[(size_t)v0 * 64 + lane] = res0;
    out[(size_t)v1 * 64 + lane] = res1;

    if (EPI == 64) {
        // t_next = h_row @ W : k ascending, ONE fma per k (Eigen gebp order)
        float a0 = 0.0f, a1 = 0.0f;
#pragma unroll
        for (int k = 0; k < 64; ++k) {
            float wk = sW[k * 64 + lane];
            a0 = fmaf(__shfl(res0, k), wk, a0);
            a1 = fmaf(__shfl(res1, k), wk, a1);
        }
        tn[(size_t)v0 * 64 + lane] = a0;
        tn[(size_t)v1 * 64 + lane] = a1;
    } else if (EPI == 1) {
        // t4 = h . W4, sequential k with FMA (r2-validated chain)
        float w4l = W[lane];
        float a0 = 0.0f, a1 = 0.0f;
#pragma unroll
        for (int k = 0; k < 64; ++k) {
            float wk = __shfl(w4l, k);
            a0 = fmaf(__shfl(res0, k), wk, a0);
            a1 = fmaf(__shfl(res1, k), wk, a1);
        }
        if (lane == 0) { tn[v0] = a0; tn[v1] = a1; }
    }
}

__global__ void agg1_k(const float* __restrict__ t4, const float* __restrict__ dis,
                       const int* __restrict__ degc, const int* __restrict__ csr,
                       const float* __restrict__ nrm,
                       const float* __restrict__ b4, float* __restrict__ h4) {
    int v = blockIdx.x * 256 + threadIdx.x;
    if (v >= Nn) return;
    int dv = min(degc[v], CAP);
    float dsv = dis[v];
    const int* row = csr + (size_t)v * CAP;
    const float* nr = nrm + (size_t)v * 64;
    float acc = 0.0f;
    int j = 0;
    for (; j + 16 <= dv; j += 16) {
        int u[16]; float nv[16], tv[16];
#pragma unroll
        for (int q = 0; q < 16; ++q) nv[q] = nr[j + q];     // independent of u
#pragma unroll
        for (int q = 0; q < 16; ++q) u[q] = row[j + q];
#pragma unroll
        for (int q = 0; q < 16; ++q) tv[q] = t4[u[q]];
#pragma unroll
        for (int q = 0; q < 16; ++q)
            acc = __fadd_rn(acc, __fmul_rn(tv[q], nv[q]));
    }
    for (; j + 4 <= dv; j += 4) {
        int u[4]; float nv[4], tv[4];
#pragma unroll
        for (int q = 0; q < 4; ++q) nv[q] = nr[j + q];
#pragma unroll
        for (int q = 0; q < 4; ++q) u[q] = row[j + q];
#pragma unroll
        for (int q = 0; q < 4; ++q) tv[q] = t4[u[q]];
#pragma unroll
        for (int q = 0; q < 4; ++q)
            acc = __fadd_rn(acc, __fmul_rn(tv[q], nv[q]));
    }
    for (; j < dv; ++j)
        acc = __fadd_rn(acc, __fmul_rn(t4[row[j]], nr[j]));
    acc = __fadd_rn(acc, __fmul_rn(t4[v], __fmul_rn(dsv, dsv)));
    h4[v] = xla_tanhf(__fadd_rn(acc, b4[0]));
}

// ------- per-graph stable top-300 sort on fp32 keys (bitonic, 512 in LDS) -----
__global__ __launch_bounds__(512) void sort_k(const float* __restrict__ h4,
                                              int* __restrict__ order) {
    __shared__ unsigned int kv[512];
    __shared__ int ki[512];
    int tid = threadIdx.x, g = blockIdx.x;
    unsigned int key = 0xFFFFFFFFu;
    if (tid < 400) {
        unsigned int u = __float_as_uint(h4[g * 400 + tid]);
        u = (u & 0x80000000u) ? ~u : (u | 0x80000000u);   // ascending map
        key = ~u;                                          // descending
    }
    kv[tid] = key; ki[tid] = tid;
    __syncthreads();
    for (int size = 2; size <= 512; size <<= 1) {
        for (int stride = size >> 1; stride > 0; stride >>= 1) {
            int p = tid ^ stride;
            if (p > tid) {
                bool asc = ((tid & size) == 0);
                unsigned int a = kv[tid], b = kv[p];
                int ia = ki[tid], ib = ki[p];
                bool gt = (a > b) || (a == b && ia > ib);   // stable tie-break
                if (gt == asc) { kv[tid] = b; kv[p] = a; ki[tid] = ib; ki[p] = ia; }
            }
            __syncthreads();
        }
    }
    if (tid < Kk) order[g * Kk + tid] = ki[tid];
}

// ---------------- conv1: z1[b,c,k] = relu(cb1[c] + sum_d feat[n,d]*cw1[c,d]) --
__global__ __launch_bounds__(128) void conv1_k(const float* __restrict__ h1,
                                               const float* __restrict__ h2,
                                               const float* __restrict__ h3,
                                               const float* __restrict__ h4,
                                               const int* __restrict__ order,
                                               const float* __restrict__ cw1,
                                               const float* __restrict__ cb1,
                                               float* __restrict__ z1) {
    __shared__ double wt[193 * 16];   // transposed [d][c]
    int tid = threadIdx.x, b = blockIdx.y;
    for (int i = tid; i < 193 * 16; i += 128) {
        int c = i / 193, d = i % 193;
        wt[d * 16 + c] = (double)cw1[i];
    }
    __syncthreads();
    int kpos = blockIdx.x * 128 + tid;
    if (kpos >= Kk) return;
    int n = b * 400 + order[b * Kk + kpos];
    double acc[16];
#pragma unroll
    for (int c = 0; c < 16; ++c) acc[c] = (double)cb1[c];
    const float* bases[3] = {h1 + (size_t)n * 64, h2 + (size_t)n * 64, h3 + (size_t)n * 64};
    for (int r = 0; r < 3; ++r) {
        const float* p = bases[r];
        for (int d = 0; d < 64; ++d) {
            double xv = (double)p[d];
            const double* wp = &wt[((size_t)r * 64 + d) * 16];
#pragma unroll
            for (int c = 0; c < 16; ++c) acc[c] += xv * wp[c];
        }
    }
    double xl = (double)h4[n];
    {
        const double* wp = &wt[192 * 16];
#pragma unroll
        for (int c = 0; c < 16; ++c) acc[c] += xl * wp[c];
    }
#pragma unroll
    for (int c = 0; c < 16; ++c)
        z1[((size_t)b * 16 + c) * 300 + kpos] = (float)fmax(acc[c], 0.0);
}

// ------- fused tail: maxpool/2 -> conv2(16->32,k5)+relu -> MLP, per graph ------
__global__ __launch_bounds__(256) void tail_k(const float* __restrict__ z1,
                                              const float* __restrict__ cw2,
                                              const float* __restrict__ cb2,
                                              const float* __restrict__ mw1,
                                              const float* __restrict__ mb1,
                                              const float* __restrict__ mw2,
                                              const float* __restrict__ mb2,
                                              float* __restrict__ out) {
    __shared__ float lz[16 * 150];
    __shared__ float lw[2560];
    __shared__ float lz3[4672];
    __shared__ double red[256];
    __shared__ double s4[32];
    int b = blockIdx.x, tid = threadIdx.x;
    for (int i = tid; i < 2400; i += 256) {
        int bc = i / 150, j = i % 150;
        const float* zp = z1 + ((size_t)b * 16 + bc) * 300 + 2 * j;
        lz[i] = fmaxf(zp[0], zp[1]);
    }
    for (int i = tid; i < 2560; i += 256) lw[i] = cw2[i];
    __syncthreads();
    for (int o = tid; o < 4672; o += 256) {
        int co = o / 146, j = o % 146;
        float acc = cb2[co];
#pragma unroll
        for (int ci = 0; ci < 16; ++ci)
#pragma unroll
            for (int tt = 0; tt < 5; ++tt)
                acc += lz[ci * 150 + j + tt] * lw[co * 80 + ci * 5 + tt];
        lz3[o] = fmaxf(acc, 0.f);
    }
    __syncthreads();
    int o = tid & 31, part = tid >> 5;   // 8 parts x 584
    double acc = 0.0;
    for (int i = part * 584; i < (part + 1) * 584; ++i)
        acc += (double)lz3[i] * (double)mw1[(size_t)i * 32 + o];
    red[tid] = acc;
    __syncthreads();
    if (tid < 32) {
        double s = 0.0;
#pragma unroll
        for (int p = 0; p < 8; ++p) s += red[p * 32 + tid];
        s4[tid] = fmax(s + (double)mb1[tid], 0.0);
    }
    __syncthreads();
    if (tid < 2) {
        double s = (double)mb2[tid];
#pragma unroll
        for (int j = 0; j < 32; ++j) s += s4[j] * (double)mw2[j * 2 + tid];
        out[b * 2 + tid] = (float)s;
    }
}

extern "C" void kernel_launch(void* const* d_in, const int* in_sizes, int n_in,
                              void* d_out, int out_size, void* d_ws, size_t ws_size,
                              hipStream_t stream) {
    const float* x   = (const float*)d_in[0];
    const int*   ei  = (const int*)d_in[1];
    const float* W1  = (const float*)d_in[2];  const float* b1  = (const float*)d_in[3];
    const float* W2  = (const float*)d_in[4];  const float* b2  = (const float*)d_in[5];
    const float* W3  = (const float*)d_in[6];  const float* b3  = (const float*)d_in[7];
    const float* W4  = (const float*)d_in[8];  const float* b4  = (const float*)d_in[9];
    const float* cw1 = (const float*)d_in[10]; const float* cb1 = (const float*)d_in[11];
    const float* cw2 = (const float*)d_in[12]; const float* cb2 = (const float*)d_in[13];
    const float* mw1 = (const float*)d_in[14]; const float* mb1 = (const float*)d_in[15];
    const float* mw2 = (const float*)d_in[16]; const float* mb2 = (const float*)d_in[17];
    float* out = (float*)d_out;

    const size_t N64 = (size_t)Nn * 64;
    float* tA   = (float*)d_ws;           // [N,64] ping
    float* tB   = tA + N64;               // [N,64] pong
    float* h1   = tB + N64;
    float* h2   = h1 + N64;
    float* h3   = h2 + N64;
    float* t4   = h3 + N64;               // [N]
    float* h4   = t4 + Nn;                // [N]
    float* dis  = h4 + Nn;                // [N]
    int*   degc = (int*)(dis + Nn);       // [N] compact degree
    int*   fill = degc + Nn;              // [N*16] padded atomic counters
    int*   csr  = fill + (size_t)Nn * 16; // [N,CAP]
    float* nrm  = (float*)(csr + (size_t)Nn * CAP);  // [N,CAP] norm per slot
    int*   order = (int*)(nrm + N64);
    float* z1 = tB;                       // tB dead after agg#2 consumed it

    hipMemsetAsync(fill, 0, sizeof(int) * (size_t)Nn * 16, stream);

    scat_k<<<Ee / 512, 256, 0, stream>>>(ei, fill, csr);
    dis_k<<<Nn / 256, 256, 0, stream>>>(fill, dis, degc);

    gemm_2w<25><<<Nn / 32, 128, 0, stream>>>(x, W1, tA);
    agg64_k<1, 64><<<Nn / 8, 256, 0, stream>>>(tA, b1, dis, degc, ei, csr, nrm, h1, W2, tB);
    agg64_k<0, 64><<<Nn / 8, 256, 0, stream>>>(tB, b2, dis, degc, ei, csr, nrm, h2, W3, tA);
    agg64_k<0, 1> <<<Nn / 8, 256, 0, stream>>>(tA, b3, dis, degc, ei, csr, nrm, h3, W4, t4);

    agg1_k<<<Nn / 256, 256, 0, stream>>>(t4, dis, degc, csr, nrm, b4, h4);

    sort_k<<<Bb, 512, 0, stream>>>(h4, order);
    conv1_k<<<dim3(3, Bb), 128, 0, stream>>>(h1, h2, h3, h4, order, cw1, cb1, z1);
    tail_k<<<Bb, 256, 0, stream>>>(z1, cw2, cb2, mw1, mb1, mw2, mb2, out);
}

// Round 9
// 986.075 us; speedup vs baseline: 1.4413x; 1.4413x over previous
//
#include <hip/hip_runtime.h>
#include <cstdint>
#include <cstddef>

#define Nn 102400
#define Ff 400
#define Ee 1638400
#define Kk 300
#define Bb 256
#define CAP 64

// XLA/Eigen f32 rational tanh approximation (ElementalIrEmitter::EmitTanh).
// Evaluated with UNFUSED mul/add (XLA emits plain fmul/fadd, no contraction),
// so CPU(np-ref) and this agree bitwise given bit-identical inputs.
__device__ __forceinline__ float xla_tanhf(float x) {
    const float c = 7.90531110763549805f;
    float xc = fminf(fmaxf(x, -c), c);
    float x2 = __fmul_rn(xc, xc);
    float p = -2.76076847742355e-16f;
    p = __fadd_rn(__fmul_rn(p, x2),  2.00018790482477e-13f);
    p = __fadd_rn(__fmul_rn(p, x2), -8.60467152213735e-11f);
    p = __fadd_rn(__fmul_rn(p, x2),  5.12229709037114e-08f);
    p = __fadd_rn(__fmul_rn(p, x2),  1.48572235717979e-05f);
    p = __fadd_rn(__fmul_rn(p, x2),  6.37261928875436e-04f);
    p = __fadd_rn(__fmul_rn(p, x2),  4.89352455891786e-03f);
    p = __fmul_rn(p, xc);
    float q = 1.19825839466702e-06f;
    q = __fadd_rn(__fmul_rn(q, x2), 1.18534705686654e-04f);
    q = __fadd_rn(__fmul_rn(q, x2), 2.26843463243900e-03f);
    q = __fadd_rn(__fmul_rn(q, x2), 4.89352518554385e-03f);
    float r = __fdiv_rn(p, q);
    return (fabsf(x) < 0.0004f) ? x : r;
}

// ---------------- CSR build: 2 edges/thread, padded fill (64B/counter) -------
__global__ void scat_k(const int* __restrict__ ei, int* __restrict__ fill,
                       int* __restrict__ csr) {
    int g = blockIdx.x * 256 + threadIdx.x;
    int2 d2 = *(const int2*)(ei + Ee + 2 * g);
    int e0 = 2 * g, e1 = 2 * g + 1;
    int p0 = atomicAdd(&fill[(size_t)d2.x * 16], 1);
    int p1 = atomicAdd(&fill[(size_t)d2.y * 16], 1);
    if (p0 < CAP) csr[(size_t)d2.x * CAP + p0] = e0;   // edge id, not src
    if (p1 < CAP) csr[(size_t)d2.y * CAP + p1] = e1;
}

// dis = 1/sqrt(deg+1) fp32 (two correctly-rounded ops = XLA-CPU rsqrt
// lowering); compact degree out of the padded counters.
__global__ void dis_k(const int* __restrict__ fill, float* __restrict__ dis,
                      int* __restrict__ degc) {
    int v = blockIdx.x * 256 + threadIdx.x;
    if (v >= Nn) return;
    int d = fill[(size_t)v * 16];
    degc[v] = d;
    dis[v] = 1.0f / sqrtf((float)(d + 1));   // +1 self loop
}

// ---- 2-wave fp32 GEMM: [M,400]@[400,64], 32x64 tile per 128-thread block,
// tile columns split across 2 waves. A/B staged into LDS once per tile.
// r7-validated win. ONE fma per k, ascending -> replicates Eigen gebp.
template <int CH>   // K = 16*CH
__global__ __launch_bounds__(128) void gemm_2w(const float* __restrict__ A,
                                               const float* __restrict__ B,
                                               float* __restrict__ C) {
    constexpr int K = 16 * CH;
    __shared__ __align__(16) float As[16 * 32];
    __shared__ __align__(16) float Bs[16 * 68];
    int tid = threadIdx.x;
    int w = tid >> 6;             // wave id: cols w*32..w*32+31
    int lane = tid & 63;
    int tx = lane & 15;           // col pair {w*32+2tx, w*32+2tx+1}
    int ty = lane >> 4;           // rows ty*8..+7
    int base = blockIdx.x * 32;
    int sr = tid >> 2, sq = tid & 3;        // A staging: row sr(0..31), k-quad sq
    int bk = tid >> 3, bn = (tid & 7) * 8;  // B staging: k-row bk(0..15), 8 cols
    float acc[8][2] = {};
    for (int ch = 0; ch < CH; ++ch) {
        int k0 = ch * 16;
        float4 av = *(const float4*)(A + (size_t)(base + sr) * K + k0 + sq * 4);
        const float* bp = B + (size_t)(k0 + bk) * 64 + bn;
        float4 b0 = *(const float4*)(bp);
        float4 b1 = *(const float4*)(bp + 4);
        __syncthreads();
        As[(sq * 4 + 0) * 32 + sr] = av.x;
        As[(sq * 4 + 1) * 32 + sr] = av.y;
        As[(sq * 4 + 2) * 32 + sr] = av.z;
        As[(sq * 4 + 3) * 32 + sr] = av.w;
        *(float4*)&Bs[bk * 68 + bn]     = b0;
        *(float4*)&Bs[bk * 68 + bn + 4] = b1;
        __syncthreads();
#pragma unroll
        for (int kk = 0; kk < 16; ++kk) {
            float4 f0 = *(const float4*)&As[kk * 32 + ty * 8];
            float4 f1 = *(const float4*)&As[kk * 32 + ty * 8 + 4];
            float2 bb = *(const float2*)&Bs[kk * 68 + w * 32 + tx * 2];
            float av8[8] = {f0.x, f0.y, f0.z, f0.w, f1.x, f1.y, f1.z, f1.w};
#pragma unroll
            for (int r = 0; r < 8; ++r) {
                acc[r][0] = fmaf(av8[r], bb.x, acc[r][0]);
                acc[r][1] = fmaf(av8[r], bb.y, acc[r][1]);
            }
        }
    }
#pragma unroll
    for (int r = 0; r < 8; ++r) {
        float* cp = C + (size_t)(base + ty * 8 + r) * 64 + w * 32 + tx * 2;
        *(float2*)cp = make_float2(acc[r][0], acc[r][1]);
    }
}

// ------- out = xla_tanh(b + segment_sum(norm_e * t[src_e]) ), fp32 exact-order.
// r7-exact body (1 row/wave, tv[32] only -> no scratch spill; r8's 2-row
// variant spilled 64-float arrays under launch_bounds(256,4): WRITE 1.74GB).
// PHASE 1 folds the old sortrow_k. Rows padded to 32 with nr=0,u=v (exact +0).
// EPI (r8-validated bit-exact): 1 = fused t4 = h.W4; 64 = fused next-layer
// GEMM t_next[v][c] = sum_k h[v][k]*W[k][c], k ascending, ONE fma per k ->
// exact Eigen gebp order (same chain the standalone gemm used).
template <int PHASE, int EPI>
__global__ __launch_bounds__(256, 4) void agg64_k(const float* __restrict__ t,
                                                  const float* __restrict__ bias,
                                                  const float* __restrict__ dis,
                                                  const int* __restrict__ degc,
                                                  const int* __restrict__ ei,
                                                  int* __restrict__ csr,
                                                  float* __restrict__ nrm,
                                                  float* __restrict__ out,
                                                  const float* __restrict__ W,
                                                  float* __restrict__ tn) {
    __shared__ int   sidx[4][64];
    __shared__ float snr[4][64];
    __shared__ float sW[EPI == 64 ? 64 * 64 : 1];
    int tid = threadIdx.x;
    int lane = tid & 63;
    int wv = __builtin_amdgcn_readfirstlane(tid >> 6);
    if (EPI == 64) {
        for (int i = tid; i < 64 * 64; i += 256) sW[i] = W[i];
        __syncthreads();   // once per block, before any LDS use
    }
    int v = blockIdx.x * 4 + wv;
    int dv = __builtin_amdgcn_readfirstlane(min(degc[v], CAP));
    float dsv = dis[v];
    float tself = t[(size_t)v * 64 + lane];   // early, independent
    float bsl = bias[lane];                   // early, independent
    int idxl;
    float nr;
    if (PHASE == 1) {
        int key = (lane < dv) ? csr[(size_t)v * CAP + lane] : 0x7FFFFFFF;
        // 64-lane bitonic sort ascending (edge ids distinct -> deterministic)
#pragma unroll
        for (int k = 2; k <= 64; k <<= 1) {
#pragma unroll
            for (int j = k >> 1; j; j >>= 1) {
                int other = __shfl_xor(key, j);
                bool up = ((lane & k) == 0);
                bool lower = ((lane & j) == 0);
                key = (lower == up) ? min(key, other) : max(key, other);
            }
        }
        idxl = v;                                    // pad u = v
        if (lane < dv) idxl = ei[key];               // src of that edge
        nr = (lane < dv) ? __fmul_rn(dis[idxl], dsv) : 0.0f;   // pad nr = 0
        csr[(size_t)v * CAP + lane] = idxl;          // sorted src row
        nrm[(size_t)v * 64 + lane] = nr;
    } else {
        idxl = (lane < dv) ? csr[(size_t)v * CAP + lane] : v;
        nr = nrm[(size_t)v * 64 + lane];             // pads are 0
    }
    sidx[wv][lane] = idxl;
    snr[wv][lane] = nr;
    // in-order DS per wave: reads below see the writes above (validated r3-r8)
    int dvp = (dv + 31) & ~31;                // 0, 32, or 64
    float acc = 0.0f;
    for (int j = 0; j < dvp; j += 32) {
        float tv[32], nv[32];
#pragma unroll
        for (int q = 0; q < 32; ++q) {
            int u = __builtin_amdgcn_readfirstlane(sidx[wv][j + q]);
            tv[q] = t[(size_t)u * 64 + lane];
        }
#pragma unroll
        for (int q = 0; q < 32; ++q) nv[q] = snr[wv][j + q];
#pragma unroll
        for (int q = 0; q < 32; ++q)
            acc = __fadd_rn(acc, __fmul_rn(tv[q], nv[q]));   // pads: +0, exact
    }
    // self-loop last (ref appends loops after edges)
    acc = __fadd_rn(acc, __fmul_rn(tself, __fmul_rn(dsv, dsv)));
    float res = xla_tanhf(__fadd_rn(acc, bsl));
    out[(size_t)v * 64 + lane] = res;
    if (EPI == 64) {
        // t_next = h_row @ W : k ascending, ONE fma per k (Eigen gebp order)
        float a = 0.0f;
#pragma unroll
        for (int k = 0; k < 64; ++k)
            a = fmaf(__shfl(res, k), sW[k * 64 + lane], a);
        tn[(size_t)v * 64 + lane] = a;
    } else if (EPI == 1) {
        // t4 = h . W4, sequential k with FMA (r2-validated chain)
        float w4l = W[lane];
        float a = 0.0f;
#pragma unroll
        for (int k = 0; k < 64; ++k)
            a = fmaf(__shfl(res, k), __shfl(w4l, k), a);
        if (lane == 0) tn[v] = a;
    }
}

__global__ void agg1_k(const float* __restrict__ t4, const float* __restrict__ dis,
                       const int* __restrict__ degc, const int* __restrict__ csr,
                       const float* __restrict__ nrm,
                       const float* __restrict__ b4, float* __restrict__ h4) {
    int v = blockIdx.x * 256 + threadIdx.x;
    if (v >= Nn) return;
    int dv = min(degc[v], CAP);
    float dsv = dis[v];
    const int* row = csr + (size_t)v * CAP;
    const float* nr = nrm + (size_t)v * 64;
    float acc = 0.0f;
    int j = 0;
    for (; j + 16 <= dv; j += 16) {
        int u[16]; float nv[16], tv[16];
#pragma unroll
        for (int q = 0; q < 16; ++q) nv[q] = nr[j + q];     // independent of u
#pragma unroll
        for (int q = 0; q < 16; ++q) u[q] = row[j + q];
#pragma unroll
        for (int q = 0; q < 16; ++q) tv[q] = t4[u[q]];
#pragma unroll
        for (int q = 0; q < 16; ++q)
            acc = __fadd_rn(acc, __fmul_rn(tv[q], nv[q]));
    }
    for (; j + 4 <= dv; j += 4) {
        int u[4]; float nv[4], tv[4];
#pragma unroll
        for (int q = 0; q < 4; ++q) nv[q] = nr[j + q];
#pragma unroll
        for (int q = 0; q < 4; ++q) u[q] = row[j + q];
#pragma unroll
        for (int q = 0; q < 4; ++q) tv[q] = t4[u[q]];
#pragma unroll
        for (int q = 0; q < 4; ++q)
            acc = __fadd_rn(acc, __fmul_rn(tv[q], nv[q]));
    }
    for (; j < dv; ++j)
        acc = __fadd_rn(acc, __fmul_rn(t4[row[j]], nr[j]));
    acc = __fadd_rn(acc, __fmul_rn(t4[v], __fmul_rn(dsv, dsv)));
    h4[v] = xla_tanhf(__fadd_rn(acc, b4[0]));
}

// ------- per-graph stable top-300 sort on fp32 keys (bitonic, 512 in LDS) -----
__global__ __launch_bounds__(512) void sort_k(const float* __restrict__ h4,
                                              int* __restrict__ order) {
    __shared__ unsigned int kv[512];
    __shared__ int ki[512];
    int tid = threadIdx.x, g = blockIdx.x;
    unsigned int key = 0xFFFFFFFFu;
    if (tid < 400) {
        unsigned int u = __float_as_uint(h4[g * 400 + tid]);
        u = (u & 0x80000000u) ? ~u : (u | 0x80000000u);   // ascending map
        key = ~u;                                          // descending
    }
    kv[tid] = key; ki[tid] = tid;
    __syncthreads();
    for (int size = 2; size <= 512; size <<= 1) {
        for (int stride = size >> 1; stride > 0; stride >>= 1) {
            int p = tid ^ stride;
            if (p > tid) {
                bool asc = ((tid & size) == 0);
                unsigned int a = kv[tid], b = kv[p];
                int ia = ki[tid], ib = ki[p];
                bool gt = (a > b) || (a == b && ia > ib);   // stable tie-break
                if (gt == asc) { kv[tid] = b; kv[p] = a; ki[tid] = ib; ki[p] = ia; }
            }
            __syncthreads();
        }
    }
    if (tid < Kk) order[g * Kk + tid] = ki[tid];
}

// ---------------- conv1: z1[b,c,k] = relu(cb1[c] + sum_d feat[n,d]*cw1[c,d]) --
__global__ __launch_bounds__(128) void conv1_k(const float* __restrict__ h1,
                                               const float* __restrict__ h2,
                                               const float* __restrict__ h3,
                                               const float* __restrict__ h4,
                                               const int* __restrict__ order,
                                               const float* __restrict__ cw1,
                                               const float* __restrict__ cb1,
                                               float* __restrict__ z1) {
    __shared__ double wt[193 * 16];   // transposed [d][c]
    int tid = threadIdx.x, b = blockIdx.y;
    for (int i = tid; i < 193 * 16; i += 128) {
        int c = i / 193, d = i % 193;
        wt[d * 16 + c] = (double)cw1[i];
    }
    __syncthreads();
    int kpos = blockIdx.x * 128 + tid;
    if (kpos >= Kk) return;
    int n = b * 400 + order[b * Kk + kpos];
    double acc[16];
#pragma unroll
    for (int c = 0; c < 16; ++c) acc[c] = (double)cb1[c];
    const float* bases[3] = {h1 + (size_t)n * 64, h2 + (size_t)n * 64, h3 + (size_t)n * 64};
    for (int r = 0; r < 3; ++r) {
        const float* p = bases[r];
        for (int d = 0; d < 64; ++d) {
            double xv = (double)p[d];
            const double* wp = &wt[((size_t)r * 64 + d) * 16];
#pragma unroll
            for (int c = 0; c < 16; ++c) acc[c] += xv * wp[c];
        }
    }
    double xl = (double)h4[n];
    {
        const double* wp = &wt[192 * 16];
#pragma unroll
        for (int c = 0; c < 16; ++c) acc[c] += xl * wp[c];
    }
#pragma unroll
    for (int c = 0; c < 16; ++c)
        z1[((size_t)b * 16 + c) * 300 + kpos] = (float)fmax(acc[c], 0.0);
}

// ------- fused tail: maxpool/2 -> conv2(16->32,k5)+relu -> MLP, per graph ------
__global__ __launch_bounds__(256) void tail_k(const float* __restrict__ z1,
                                              const float* __restrict__ cw2,
                                              const float* __restrict__ cb2,
                                              const float* __restrict__ mw1,
                                              const float* __restrict__ mb1,
                                              const float* __restrict__ mw2,
                                              const float* __restrict__ mb2,
                                              float* __restrict__ out) {
    __shared__ float lz[16 * 150];
    __shared__ float lw[2560];
    __shared__ float lz3[4672];
    __shared__ double red[256];
    __shared__ double s4[32];
    int b = blockIdx.x, tid = threadIdx.x;
    for (int i = tid; i < 2400; i += 256) {
        int bc = i / 150, j = i % 150;
        const float* zp = z1 + ((size_t)b * 16 + bc) * 300 + 2 * j;
        lz[i] = fmaxf(zp[0], zp[1]);
    }
    for (int i = tid; i < 2560; i += 256) lw[i] = cw2[i];
    __syncthreads();
    for (int o = tid; o < 4672; o += 256) {
        int co = o / 146, j = o % 146;
        float acc = cb2[co];
#pragma unroll
        for (int ci = 0; ci < 16; ++ci)
#pragma unroll
            for (int tt = 0; tt < 5; ++tt)
                acc += lz[ci * 150 + j + tt] * lw[co * 80 + ci * 5 + tt];
        lz3[o] = fmaxf(acc, 0.f);
    }
    __syncthreads();
    int o = tid & 31, part = tid >> 5;   // 8 parts x 584
    double acc = 0.0;
    for (int i = part * 584; i < (part + 1) * 584; ++i)
        acc += (double)lz3[i] * (double)mw1[(size_t)i * 32 + o];
    red[tid] = acc;
    __syncthreads();
    if (tid < 32) {
        double s = 0.0;
#pragma unroll
        for (int p = 0; p < 8; ++p) s += red[p * 32 + tid];
        s4[tid] = fmax(s + (double)mb1[tid], 0.0);
    }
    __syncthreads();
    if (tid < 2) {
        double s = (double)mb2[tid];
#pragma unroll
        for (int j = 0; j < 32; ++j) s += s4[j] * (double)mw2[j * 2 + tid];
        out[b * 2 + tid] = (float)s;
    }
}

extern "C" void kernel_launch(void* const* d_in, const int* in_sizes, int n_in,
                              void* d_out, int out_size, void* d_ws, size_t ws_size,
                              hipStream_t stream) {
    const float* x   = (const float*)d_in[0];
    const int*   ei  = (const int*)d_in[1];
    const float* W1  = (const float*)d_in[2];  const float* b1  = (const float*)d_in[3];
    const float* W2  = (const float*)d_in[4];  const float* b2  = (const float*)d_in[5];
    const float* W3  = (const float*)d_in[6];  const float* b3  = (const float*)d_in[7];
    const float* W4  = (const float*)d_in[8];  const float* b4  = (const float*)d_in[9];
    const float* cw1 = (const float*)d_in[10]; const float* cb1 = (const float*)d_in[11];
    const float* cw2 = (const float*)d_in[12]; const float* cb2 = (const float*)d_in[13];
    const float* mw1 = (const float*)d_in[14]; const float* mb1 = (const float*)d_in[15];
    const float* mw2 = (const float*)d_in[16]; const float* mb2 = (const float*)d_in[17];
    float* out = (float*)d_out;

    const size_t N64 = (size_t)Nn * 64;
    float* tA   = (float*)d_ws;           // [N,64] ping
    float* tB   = tA + N64;               // [N,64] pong
    float* h1   = tB + N64;
    float* h2   = h1 + N64;
    float* h3   = h2 + N64;
    float* t4   = h3 + N64;               // [N]
    float* h4   = t4 + Nn;                // [N]
    float* dis  = h4 + Nn;                // [N]
    int*   degc = (int*)(dis + Nn);       // [N] compact degree
    int*   fill = degc + Nn;              // [N*16] padded atomic counters
    int*   csr  = fill + (size_t)Nn * 16; // [N,CAP]
    float* nrm  = (float*)(csr + (size_t)Nn * CAP);  // [N,CAP] norm per slot
    int*   order = (int*)(nrm + N64);
    float* z1 = tB;                       // tB dead after agg#2 consumed it

    hipMemsetAsync(fill, 0, sizeof(int) * (size_t)Nn * 16, stream);

    scat_k<<<Ee / 512, 256, 0, stream>>>(ei, fill, csr);
    dis_k<<<Nn / 256, 256, 0, stream>>>(fill, dis, degc);

    gemm_2w<25><<<Nn / 32, 128, 0, stream>>>(x, W1, tA);
    agg64_k<1, 64><<<Nn / 4, 256, 0, stream>>>(tA, b1, dis, degc, ei, csr, nrm, h1, W2, tB);
    agg64_k<0, 64><<<Nn / 4, 256, 0, stream>>>(tB, b2, dis, degc, ei, csr, nrm, h2, W3, tA);
    agg64_k<0, 1> <<<Nn / 4, 256, 0, stream>>>(tA, b3, dis, degc, ei, csr, nrm, h3, W4, t4);

    agg1_k<<<Nn / 256, 256, 0, stream>>>(t4, dis, degc, csr, nrm, b4, h4);

    sort_k<<<Bb, 512, 0, stream>>>(h4, order);
    conv1_k<<<dim3(3, Bb), 128, 0, stream>>>(h1, h2, h3, h4, order, cw1, cb1, z1);
    tail_k<<<Bb, 256, 0, stream>>>(z1, cw2, cb2, mw1, mb1, mw2, mb2, out);
}